// Round 5
// baseline (76.008 us; speedup 1.0000x reference)
//
#include <hip/hip_runtime.h>
#include <math.h>

#define NB   4
#define SL   1024
#define NTOK (NB*SL)      // 4096
#define DM   64           // d_model
#define DI   128          // d_inner
#define DSt  128          // d_state
#define SEGLEN 16
#define NSEG (SL/SEGLEN)  // 64

// ---- workspace layout (float offsets); ~10.8 MB total, no aliasing ----
#define OFF_GATE   0
#define OFF_DELTA  (OFF_GATE  + NTOK*DI)
#define OFF_BM     (OFF_DELTA + NTOK*DI)
#define OFF_CM     (OFF_BM    + NTOK*DSt)
#define OFF_XPOOL  (OFF_CM    + NTOK*DSt)
#define OFF_ABAR   (OFF_XPOOL + NTOK)
#define OFF_HEND   (OFF_ABAR  + NTOK*DSt)    // NB*NSEG*DSt = 32768
#define OFF_P      (OFF_HEND  + NB*NSEG*DSt) // 32768

#define PROJ_TOK 32
#define PROJ_TG  (NTOK/PROJ_TOK)   // 128 token groups

static __device__ __forceinline__ float wave64_sum(float v) {
#pragma unroll
    for (int m = 32; m >= 1; m >>= 1) v += __shfl_xor(v, m, 64);
    return v;
}

static __device__ __forceinline__ float fast_exp2(float x) {
    float r;
    asm("v_exp_f32 %0, %1" : "=v"(r) : "v"(x));
    return r;
}

// ---- K1: projections. grid = 4 cats x 128 token-groups.
// All global traffic coalesced: x tile -> LDS, W panel -> LDS (then swizzled
// ds_read_b128 into per-lane VGPRs). Lane l owns rows l, l+64; stores coalesced.
__global__ __launch_bounds__(256) void k_proj(
    const float* __restrict__ x, const float* __restrict__ W_in,
    const float* __restrict__ W_delta, const float* __restrict__ b_delta,
    const float* __restrict__ W_B, const float* __restrict__ b_B,
    const float* __restrict__ W_C, const float* __restrict__ b_C,
    float* __restrict__ ws)
{
    __shared__ float  xl[PROJ_TOK*DM];   // 8 KB
    __shared__ float4 Wl[DI*16];         // 32 KB, [row][k ^ (row&15)]
    const int tid = threadIdx.x;
    const int l   = tid & 63;
    const int w   = tid >> 6;
    const int cat = blockIdx.x >> 7;     // 0 gate, 1 delta, 2 B, 3 C
    const int tg  = blockIdx.x & (PROJ_TG-1);
    const int tok0 = tg * PROJ_TOK;

    const float* Wbase; const float* bias; float* dst;
    if      (cat == 0) { Wbase = W_in + DI*DM; bias = nullptr; dst = ws + OFF_GATE;  }
    else if (cat == 1) { Wbase = W_delta;      bias = b_delta; dst = ws + OFF_DELTA; }
    else if (cat == 2) { Wbase = W_B;          bias = b_B;     dst = ws + OFF_BM;    }
    else               { Wbase = W_C;          bias = b_C;     dst = ws + OFF_CM;    }

    // stage x tile (512 f4) and weight panel (2048 f4), both fully coalesced
    {
        const float4* xg = (const float4*)(x + tok0*DM);
        float4* xl4 = (float4*)xl;
        xl4[tid]       = xg[tid];
        xl4[tid + 256] = xg[tid + 256];
        const float4* Wg = (const float4*)Wbase;
#pragma unroll
        for (int j = 0; j < 8; ++j) {
            const int f = tid + j*256;          // float4 index 0..2047
            const int row = f >> 4, k = f & 15;
            Wl[row*16 + (k ^ (row & 15))] = Wg[f];
        }
    }
    __syncthreads();

    // per-lane weight rows l and l+64 -> VGPRs via swizzled (2-way max) reads
    float4 w0[16], w1[16];
#pragma unroll
    for (int k = 0; k < 16; ++k) {
        w0[k] = Wl[l*16      + (k ^ (l & 15))];
        w1[k] = Wl[(l+64)*16 + (k ^ (l & 15))];
    }
    float bias0 = 0.f, bias1 = 0.f;
    if (bias) { bias0 = bias[l]; bias1 = bias[l+64]; }

#pragma unroll 2
    for (int it = 0; it < PROJ_TOK/4; ++it) {
        const int tl = it*4 + w;        // wave-uniform local token
        float a0=0.f,a1=0.f,a2=0.f,a3=0.f, c0=0.f,c1=0.f,c2=0.f,c3=0.f;
#pragma unroll
        for (int k = 0; k < 16; ++k) {
            const float4 xv = *(const float4*)(xl + tl*DM + 4*k);  // broadcast
            a0 = fmaf(w0[k].x, xv.x, a0);
            a1 = fmaf(w0[k].y, xv.y, a1);
            a2 = fmaf(w0[k].z, xv.z, a2);
            a3 = fmaf(w0[k].w, xv.w, a3);
            c0 = fmaf(w1[k].x, xv.x, c0);
            c1 = fmaf(w1[k].y, xv.y, c1);
            c2 = fmaf(w1[k].z, xv.z, c2);
            c3 = fmaf(w1[k].w, xv.w, c3);
        }
        float ra = (a0+a1) + (a2+a3) + bias0;
        float rb = (c0+c1) + (c2+c3) + bias1;
        if (cat == 1) {  // softplus, numerically stable
            ra = fmaxf(ra, 0.f) + log1pf(__expf(-fabsf(ra)));
            rb = fmaxf(rb, 0.f) + log1pf(__expf(-fabsf(rb)));
        }
        const int tok = tok0 + tl;
        dst[tok*128 + l]      = ra;   // coalesced 256B
        dst[tok*128 + 64 + l] = rb;   // coalesced 256B
    }

    if (cat == 0) {   // x_pool = x . w_pool (mean over x_ssm dims folded into W)
        float wp = 0.f;
#pragma unroll 8
        for (int i = 0; i < DI; ++i) wp += W_in[i*DM + l];   // coalesced
        wp *= (1.0f/DI);
#pragma unroll
        for (int it = 0; it < PROJ_TOK/4; ++it) {
            const int tl = it*4 + w;
            float v = xl[tl*DM + l] * wp;   // stride-1: conflict-free
            v = wave64_sum(v);
            if (l == 0) ws[OFF_XPOOL + tok0 + tl] = v;
        }
    }
}

// ---- K2: fused Abar + scan pass 1. Block = one segment (16 tokens).
// Phase 1: Abar[t,s] = mean_i 2^(delta[t,i] * A[i,s]*log2e), A col in VGPRs;
//          result kept in LDS and written to global (pass 2 needs it).
// Phase 2: 16-step local scan from LDS; write HEND/P. ----
__global__ __launch_bounds__(256, 2) void k_abar_scan1(const float* __restrict__ A,
                                                       float* __restrict__ ws)
{
    __shared__ float ab_lds[SEGLEN][DSt];   // 8 KB
    const int tid  = threadIdx.x;
    const int s    = tid & 127;
    const int half = tid >> 7;
    const int b    = blockIdx.x >> 6;
    const int seg  = blockIdx.x & 63;
    const int t0   = b*SL + seg*SEGLEN;

    float areg[DI];
#pragma unroll
    for (int i = 0; i < DI; ++i) areg[i] = A[i*DSt + s] * 1.44269504f;  // fold log2e

    const float* delta = ws + OFF_DELTA;
    float*       Abar  = ws + OFF_ABAR;
#pragma unroll 2
    for (int p = 0; p < 8; ++p) {
        const int tl = half*8 + p;
        const float* dv = delta + (t0 + tl)*DI;
        float a0 = 0.f, a1 = 0.f, a2 = 0.f, a3 = 0.f;
#pragma unroll
        for (int i4 = 0; i4 < DI/4; ++i4) {
            const float4 d4 = *(const float4*)(dv + 4*i4);  // wave-uniform bcast
            a0 += fast_exp2(d4.x * areg[4*i4    ]);
            a1 += fast_exp2(d4.y * areg[4*i4 + 1]);
            a2 += fast_exp2(d4.z * areg[4*i4 + 2]);
            a3 += fast_exp2(d4.w * areg[4*i4 + 3]);
        }
        const float ab = ((a0+a1) + (a2+a3)) * (1.0f/DI);
        ab_lds[tl][s] = ab;
        Abar[(t0 + tl)*DSt + s] = ab;       // coalesced 256B per wave
    }
    __syncthreads();

    if (tid < 128) {                        // phase 2: local scan over 16 steps
        const float* Bm    = ws + OFF_BM;
        const float* xpool = ws + OFF_XPOOL;
        float bx[SEGLEN];
#pragma unroll
        for (int t = 0; t < SEGLEN; ++t)    // independent, pipelined loads
            bx[t] = Bm[(t0 + t)*DSt + s] * xpool[t0 + t];
        float h = 0.f, pr = 1.f;
#pragma unroll
        for (int t = 0; t < SEGLEN; ++t) {
            const float a = ab_lds[t][s];   // conflict-free
            h = fmaf(a, h, bx[t]);
            pr *= a;
        }
        ws[OFF_HEND + blockIdx.x*DSt + s] = h;
        ws[OFF_P    + blockIdx.x*DSt + s] = pr;
    }
}

// ---- K3: fused scan pass 2 + output. Block = 256 threads = 2 segments.
// Phase A: prefetch rescan operands -> stitch -> pure-VALU rescan -> y reduce.
// Phase B: y*silu(gate) @ W_out^T + residual + LayerNorm, wave per token. ----
__global__ __launch_bounds__(256) void k_scan2_out(
    const float* __restrict__ x, const float* __restrict__ W_out,
    const float* __restrict__ ln_w, const float* __restrict__ ln_b,
    float* __restrict__ ws, float* __restrict__ out)
{
    __shared__ float  prod[2*SEGLEN][132];
    __shared__ float4 Wl[DM*32];          // [row][c4 ^ (row&7)]
    __shared__ float  vbuf[4][DI];
    __shared__ float  y_lds[2*SEGLEN];

    const int tid   = threadIdx.x;
    const int lane  = tid & 63;
    const int w     = tid >> 6;
    const int shalf = tid & 127;          // state index within segment
    const int wp    = tid >> 7;           // which of 2 segments
    const int b     = blockIdx.x >> 5;
    const int sg    = blockIdx.x & 31;
    const int seg   = sg*2 + wp;

    // stage W_out (2048 f4, coalesced -> swizzled)
    const float4* W4g = (const float4*)W_out;
#pragma unroll
    for (int j = 0; j < 8; ++j) {
        const int f = tid + j*256;
        const int row = f >> 5, c4 = f & 31;
        Wl[row*32 + (c4 ^ (row & 7))] = W4g[f];
    }

    const float* Abar  = ws + OFF_ABAR;
    const float* Bm    = ws + OFF_BM;
    const float* Cm    = ws + OFF_CM;
    const float* xpool = ws + OFF_XPOOL;
    const float* hend  = ws + OFF_HEND;
    const float* P     = ws + OFF_P;

    const int t0 = b*SL + seg*SEGLEN;

    // prefetch all rescan operands (independent loads, overlap the stitch)
    float aA[SEGLEN], aB[SEGLEN], aC[SEGLEN];
#pragma unroll
    for (int t = 0; t < SEGLEN; ++t) {
        aA[t] = Abar[(t0 + t)*DSt + shalf];
        aB[t] = Bm[(t0 + t)*DSt + shalf] * xpool[t0 + t];
        aC[t] = Cm[(t0 + t)*DSt + shalf];
    }

    // phase A: prefix stitch (wave-uniform trip count, batched loads)
    float h = 0.f;
#pragma unroll 8
    for (int j = 0; j < seg; ++j) {
        const int idx = (b*NSEG + j)*DSt + shalf;
        h = fmaf(P[idx], h, hend[idx]);
    }
    // rescan (pure VALU)
#pragma unroll
    for (int t = 0; t < SEGLEN; ++t) {
        h = fmaf(aA[t], h, aB[t]);
        prod[wp*SEGLEN + t][shalf] = aC[t] * h;
    }
    __syncthreads();

    // y reduce: 8 lanes per token
    {
        const int t = shalf >> 3, r = lane & 7;
        const int row = wp*SEGLEN + t;
        float4 acc4 = {0.f,0.f,0.f,0.f};
#pragma unroll
        for (int k4 = 0; k4 < 4; ++k4) {
            const float4 v = *(const float4*)(&prod[row][r*16 + 4*k4]);
            acc4.x += v.x; acc4.y += v.y; acc4.z += v.z; acc4.w += v.w;
        }
        float acc = (acc4.x + acc4.y) + (acc4.z + acc4.w);
#pragma unroll
        for (int m = 1; m <= 4; m <<= 1) acc += __shfl_xor(acc, m, 64);
        if (r == 0) y_lds[row] = acc;
    }
    __syncthreads();

    // phase B: 8 tokens per wave
    const float* gate = ws + OFF_GATE;
    const int d = lane;
    const float lw = ln_w[d], lb = ln_b[d];
#pragma unroll 2
    for (int j = 0; j < 8; ++j) {
        const int tloc = w*8 + j;
        const int tok  = b*SL + sg*32 + tloc;
        const float yt = y_lds[tloc];
        const float g0 = gate[tok*DI + d];
        const float g1 = gate[tok*DI + 64 + d];
        vbuf[w][d]      = yt * (g0 / (1.f + __expf(-g0)));   // wave-private
        vbuf[w][64 + d] = yt * (g1 / (1.f + __expf(-g1)));

        float ac0 = 0.f, ac1 = 0.f, ac2 = 0.f, ac3 = 0.f;
#pragma unroll 8
        for (int q = 0; q < 32; ++q) {
            const float4 wv = Wl[d*32 + (q ^ (d & 7))];        // spread banks
            const float4 vv = *(const float4*)(&vbuf[w][q*4]); // broadcast
            ac0 = fmaf(wv.x, vv.x, ac0);
            ac1 = fmaf(wv.y, vv.y, ac1);
            ac2 = fmaf(wv.z, vv.z, ac2);
            ac3 = fmaf(wv.w, vv.w, ac3);
        }
        const float z  = (ac0+ac1) + (ac2+ac3) + x[tok*DM + d];
        const float s1 = wave64_sum(z);
        const float s2 = wave64_sum(z*z);
        const float mu  = s1 * (1.f/64.f);
        const float var = s2 * (1.f/64.f) - mu*mu;
        out[tok*DM + d] = (z - mu) * rsqrtf(var + 1e-5f) * lw + lb;
    }
}

extern "C" void kernel_launch(void* const* d_in, const int* in_sizes, int n_in,
                              void* d_out, int out_size, void* d_ws, size_t ws_size,
                              hipStream_t stream) {
    const float* x       = (const float*)d_in[0];
    const float* W_in    = (const float*)d_in[1];
    const float* W_delta = (const float*)d_in[2];
    const float* b_delta = (const float*)d_in[3];
    const float* W_B     = (const float*)d_in[4];
    const float* b_B     = (const float*)d_in[5];
    const float* W_C     = (const float*)d_in[6];
    const float* b_C     = (const float*)d_in[7];
    const float* A       = (const float*)d_in[8];
    const float* W_out   = (const float*)d_in[9];
    const float* ln_w    = (const float*)d_in[10];
    const float* ln_b    = (const float*)d_in[11];
    float* out = (float*)d_out;
    float* ws  = (float*)d_ws;

    hipLaunchKernelGGL(k_proj,       dim3(4*PROJ_TG), dim3(256), 0, stream,
                       x, W_in, W_delta, b_delta, W_B, b_B, W_C, b_C, ws);
    hipLaunchKernelGGL(k_abar_scan1, dim3(NB*NSEG),   dim3(256), 0, stream, A, ws);
    hipLaunchKernelGGL(k_scan2_out,  dim3(128),       dim3(256), 0, stream,
                       x, W_out, ln_w, ln_b, ws, out);
}

// Round 6
// 59.382 us; speedup vs baseline: 1.2800x; 1.2800x over previous
//
#include <hip/hip_runtime.h>
#include <math.h>

#define NB   4
#define SL   1024
#define NTOK (NB*SL)      // 4096
#define DM   64           // d_model
#define DI   128          // d_inner
#define DSt  128          // d_state
#define SEGLEN 16
#define NSEG (SL/SEGLEN)  // 64

// ---- workspace layout (float offsets); ~10.8 MB total ----
#define OFF_GATE   0
#define OFF_DELTA  (OFF_GATE  + NTOK*DI)
#define OFF_BM     (OFF_DELTA + NTOK*DI)
#define OFF_CM     (OFF_BM    + NTOK*DSt)
#define OFF_XPOOL  (OFF_CM    + NTOK*DSt)
#define OFF_ABAR   (OFF_XPOOL + NTOK)
#define OFF_HEND   (OFF_ABAR  + NTOK*DSt)
#define OFF_P      (OFF_HEND  + NB*NSEG*DSt)

#define PROJ_TOK 32
#define PROJ_TG  (NTOK/PROJ_TOK)   // 128 token groups

static __device__ __forceinline__ float wave64_sum(float v) {
#pragma unroll
    for (int m = 32; m >= 1; m >>= 1) v += __shfl_xor(v, m, 64);
    return v;
}

static __device__ __forceinline__ float fast_exp2(float x) {
    float r;
    asm("v_exp_f32 %0, %1" : "=v"(r) : "v"(x));
    return r;
}

// softplus via native transcendentals (tolerance 0.088 >> 1e-6 error)
static __device__ __forceinline__ float softplus_f(float x) {
    return fmaxf(x, 0.f) + __logf(1.f + __expf(-fabsf(x)));
}

// ---- K1: projections. grid = (4 cats x 2 row-halves) x 128 token-groups.
// ONE row per lane -> 64 weight VGPRs (fits; no remat). x tile + 64-row W
// panel staged coalesced in LDS; x read as wave-uniform broadcast; W rows
// read once via XOR-swizzled ds_read_b128; stores coalesced.
__global__ __launch_bounds__(256) void k_proj(
    const float* __restrict__ x, const float* __restrict__ W_in,
    const float* __restrict__ W_delta, const float* __restrict__ b_delta,
    const float* __restrict__ W_B, const float* __restrict__ b_B,
    const float* __restrict__ W_C, const float* __restrict__ b_C,
    float* __restrict__ ws)
{
    __shared__ float  xl[PROJ_TOK*DM];   // 8 KB
    __shared__ float4 Wl[64*16];         // 16 KB, [row][k ^ (row&15)]
    const int tid = threadIdx.x;
    const int l   = tid & 63;
    const int w   = tid >> 6;
    const int rg  = blockIdx.x >> 7;     // 0..7: cat*2 + row-half
    const int tg  = blockIdx.x & 127;
    const int cat = rg >> 1;
    const int r0  = (rg & 1) * 64;
    const int tok0 = tg * PROJ_TOK;

    const float* Wbase; const float* bias; float* dst;
    if      (cat == 0) { Wbase = W_in + DI*DM; bias = nullptr; dst = ws + OFF_GATE;  }
    else if (cat == 1) { Wbase = W_delta;      bias = b_delta; dst = ws + OFF_DELTA; }
    else if (cat == 2) { Wbase = W_B;          bias = b_B;     dst = ws + OFF_BM;    }
    else               { Wbase = W_C;          bias = b_C;     dst = ws + OFF_CM;    }

    // stage x tile (512 f4) and 64-row weight panel (1024 f4), coalesced
    {
        const float4* xg = (const float4*)(x + tok0*DM);
        float4* xl4 = (float4*)xl;
        xl4[tid]       = xg[tid];
        xl4[tid + 256] = xg[tid + 256];
        const float4* Wg = (const float4*)(Wbase + r0*DM);
#pragma unroll
        for (int j = 0; j < 4; ++j) {
            const int f = tid + j*256;          // f4 index 0..1023
            const int row = f >> 4, k = f & 15;
            Wl[row*16 + (k ^ (row & 15))] = Wg[f];
        }
    }
    __syncthreads();

    // this lane's single weight row -> 16 f4 = 64 VGPRs
    float4 wr[16];
#pragma unroll
    for (int k = 0; k < 16; ++k) wr[k] = Wl[l*16 + (k ^ (l & 15))];
    const float bias0 = bias ? bias[r0 + l] : 0.f;

#pragma unroll
    for (int it = 0; it < PROJ_TOK/4; ++it) {
        const int tl = it*4 + w;        // wave-uniform local token
        float a0=0.f,a1=0.f,a2=0.f,a3=0.f;
#pragma unroll
        for (int k = 0; k < 16; ++k) {
            const float4 xv = *(const float4*)(xl + tl*DM + 4*k);  // broadcast
            a0 = fmaf(wr[k].x, xv.x, a0);
            a1 = fmaf(wr[k].y, xv.y, a1);
            a2 = fmaf(wr[k].z, xv.z, a2);
            a3 = fmaf(wr[k].w, xv.w, a3);
        }
        float ra = (a0+a1) + (a2+a3) + bias0;
        if (cat == 1) ra = softplus_f(ra);
        dst[(tok0 + tl)*128 + r0 + l] = ra;   // coalesced 256B
    }

    if (rg == 0) {   // x_pool = x . w_pool (mean over x_ssm dims folded into W)
        float wp = 0.f;
#pragma unroll 8
        for (int i = 0; i < DI; ++i) wp += W_in[i*DM + l];   // coalesced
        wp *= (1.0f/DI);
#pragma unroll
        for (int it = 0; it < PROJ_TOK/4; ++it) {
            const int tl = it*4 + w;
            float v = xl[tl*DM + l] * wp;   // stride-1: conflict-free
            v = wave64_sum(v);
            if (l == 0) ws[OFF_XPOOL + tok0 + tl] = v;
        }
    }
}

// ---- K2: fused Abar + scan pass 1. Block = one segment (16 tokens),
// 512 threads = 2 s-halves x 4 i-groups -> areg[32] per lane (no spill/remat).
// Partials reduced via LDS; Abar kept in LDS for the 16-step local scan. ----
__global__ __launch_bounds__(512) void k_abar_scan1(const float* __restrict__ A,
                                                    float* __restrict__ ws)
{
    __shared__ float psum[4][8][DSt];       // 16 KB
    __shared__ float ab_lds[SEGLEN][DSt];   // 8 KB
    const int tid  = threadIdx.x;
    const int lane = tid & 63;
    const int w    = tid >> 6;              // 0..7
    const int sgrp = w & 1;
    const int igrp = w >> 1;                // 0..3
    const int s    = sgrp*64 + lane;
    const int b    = blockIdx.x >> 6;
    const int seg  = blockIdx.x & 63;
    const int t0   = b*SL + seg*SEGLEN;

    // 32 A values per lane, log2e folded
    float areg[32];
#pragma unroll
    for (int i = 0; i < 32; ++i)
        areg[i] = A[(igrp*32 + i)*DSt + s] * 1.44269504f;   // coalesced

    const float* delta = ws + OFF_DELTA;
    float*       Abar  = ws + OFF_ABAR;

    for (int hp = 0; hp < 2; ++hp) {        // two half-phases of 8 tokens
#pragma unroll
        for (int t = 0; t < 8; ++t) {
            const float* dv = delta + (t0 + hp*8 + t)*DI + igrp*32;
            float a0=0.f,a1=0.f,a2=0.f,a3=0.f;
#pragma unroll
            for (int q = 0; q < 8; ++q) {
                const float4 d4 = *(const float4*)(dv + 4*q);  // uniform bcast
                a0 += fast_exp2(d4.x * areg[4*q    ]);
                a1 += fast_exp2(d4.y * areg[4*q + 1]);
                a2 += fast_exp2(d4.z * areg[4*q + 2]);
                a3 += fast_exp2(d4.w * areg[4*q + 3]);
            }
            psum[igrp][t][s] = (a0+a1) + (a2+a3);   // consecutive s: no conflict
        }
        __syncthreads();
        {   // reduce 4 i-groups; write Abar (LDS + global, both coalesced)
            const int s2 = tid & 127, tq = tid >> 7;   // 4 token-pairs
#pragma unroll
            for (int j = 0; j < 2; ++j) {
                const int t = tq*2 + j;
                float v = (psum[0][t][s2] + psum[1][t][s2])
                        + (psum[2][t][s2] + psum[3][t][s2]);
                v *= (1.0f/DI);
                ab_lds[hp*8 + t][s2] = v;
                Abar[(t0 + hp*8 + t)*DSt + s2] = v;
            }
        }
        __syncthreads();   // psum reused next half-phase
    }

    if (tid < 128) {        // phase 3: 16-step local scan
        const int s2 = tid;
        const float* Bm    = ws + OFF_BM;
        const float* xpool = ws + OFF_XPOOL;
        float bx[SEGLEN];
#pragma unroll
        for (int t = 0; t < SEGLEN; ++t)
            bx[t] = Bm[(t0 + t)*DSt + s2] * xpool[t0 + t];
        float h = 0.f, pr = 1.f;
#pragma unroll
        for (int t = 0; t < SEGLEN; ++t) {
            const float a = ab_lds[t][s2];
            h = fmaf(a, h, bx[t]);
            pr *= a;
        }
        ws[OFF_HEND + blockIdx.x*DSt + s2] = h;
        ws[OFF_P    + blockIdx.x*DSt + s2] = pr;
    }
}

// ---- K3: fused scan pass 2 + output. Block = 256 threads = 2 segments. ----
__global__ __launch_bounds__(256) void k_scan2_out(
    const float* __restrict__ x, const float* __restrict__ W_out,
    const float* __restrict__ ln_w, const float* __restrict__ ln_b,
    float* __restrict__ ws, float* __restrict__ out)
{
    __shared__ float  prod[2*SEGLEN][132];
    __shared__ float4 Wl[DM*32];          // [row][c4 ^ (row&7)]
    __shared__ float  vbuf[4][DI];
    __shared__ float  y_lds[2*SEGLEN];

    const int tid   = threadIdx.x;
    const int lane  = tid & 63;
    const int w     = tid >> 6;
    const int shalf = tid & 127;
    const int wp    = tid >> 7;
    const int b     = blockIdx.x >> 5;
    const int sg    = blockIdx.x & 31;
    const int seg   = sg*2 + wp;

    const float4* W4g = (const float4*)W_out;
#pragma unroll
    for (int j = 0; j < 8; ++j) {
        const int f = tid + j*256;
        const int row = f >> 5, c4 = f & 31;
        Wl[row*32 + (c4 ^ (row & 7))] = W4g[f];
    }

    const float* Abar  = ws + OFF_ABAR;
    const float* Bm    = ws + OFF_BM;
    const float* Cm    = ws + OFF_CM;
    const float* xpool = ws + OFF_XPOOL;
    const float* hend  = ws + OFF_HEND;
    const float* P     = ws + OFF_P;

    const int t0 = b*SL + seg*SEGLEN;

    float aA[SEGLEN], aB[SEGLEN], aC[SEGLEN];
#pragma unroll
    for (int t = 0; t < SEGLEN; ++t) {
        aA[t] = Abar[(t0 + t)*DSt + shalf];
        aB[t] = Bm[(t0 + t)*DSt + shalf] * xpool[t0 + t];
        aC[t] = Cm[(t0 + t)*DSt + shalf];
    }

    float h = 0.f;
#pragma unroll 8
    for (int j = 0; j < seg; ++j) {
        const int idx = (b*NSEG + j)*DSt + shalf;
        h = fmaf(P[idx], h, hend[idx]);
    }
#pragma unroll
    for (int t = 0; t < SEGLEN; ++t) {
        h = fmaf(aA[t], h, aB[t]);
        prod[wp*SEGLEN + t][shalf] = aC[t] * h;
    }
    __syncthreads();

    {
        const int t = shalf >> 3, r = lane & 7;
        const int row = wp*SEGLEN + t;
        float4 acc4 = {0.f,0.f,0.f,0.f};
#pragma unroll
        for (int k4 = 0; k4 < 4; ++k4) {
            const float4 v = *(const float4*)(&prod[row][r*16 + 4*k4]);
            acc4.x += v.x; acc4.y += v.y; acc4.z += v.z; acc4.w += v.w;
        }
        float acc = (acc4.x + acc4.y) + (acc4.z + acc4.w);
#pragma unroll
        for (int m = 1; m <= 4; m <<= 1) acc += __shfl_xor(acc, m, 64);
        if (r == 0) y_lds[row] = acc;
    }
    __syncthreads();

    const float* gate = ws + OFF_GATE;
    const int d = lane;
    const float lw = ln_w[d], lb = ln_b[d];
#pragma unroll 2
    for (int j = 0; j < 8; ++j) {
        const int tloc = w*8 + j;
        const int tok  = b*SL + sg*32 + tloc;
        const float yt = y_lds[tloc];
        const float g0 = gate[tok*DI + d];
        const float g1 = gate[tok*DI + 64 + d];
        vbuf[w][d]      = yt * (g0 / (1.f + __expf(-g0)));
        vbuf[w][64 + d] = yt * (g1 / (1.f + __expf(-g1)));

        float ac0 = 0.f, ac1 = 0.f, ac2 = 0.f, ac3 = 0.f;
#pragma unroll 8
        for (int q = 0; q < 32; ++q) {
            const float4 wv = Wl[d*32 + (q ^ (d & 7))];
            const float4 vv = *(const float4*)(&vbuf[w][q*4]);
            ac0 = fmaf(wv.x, vv.x, ac0);
            ac1 = fmaf(wv.y, vv.y, ac1);
            ac2 = fmaf(wv.z, vv.z, ac2);
            ac3 = fmaf(wv.w, vv.w, ac3);
        }
        const float z  = (ac0+ac1) + (ac2+ac3) + x[tok*DM + d];
        const float s1 = wave64_sum(z);
        const float s2 = wave64_sum(z*z);
        const float mu  = s1 * (1.f/64.f);
        const float var = s2 * (1.f/64.f) - mu*mu;
        out[tok*DM + d] = (z - mu) * rsqrtf(var + 1e-5f) * lw + lb;
    }
}

extern "C" void kernel_launch(void* const* d_in, const int* in_sizes, int n_in,
                              void* d_out, int out_size, void* d_ws, size_t ws_size,
                              hipStream_t stream) {
    const float* x       = (const float*)d_in[0];
    const float* W_in    = (const float*)d_in[1];
    const float* W_delta = (const float*)d_in[2];
    const float* b_delta = (const float*)d_in[3];
    const float* W_B     = (const float*)d_in[4];
    const float* b_B     = (const float*)d_in[5];
    const float* W_C     = (const float*)d_in[6];
    const float* b_C     = (const float*)d_in[7];
    const float* A       = (const float*)d_in[8];
    const float* W_out   = (const float*)d_in[9];
    const float* ln_w    = (const float*)d_in[10];
    const float* ln_b    = (const float*)d_in[11];
    float* out = (float*)d_out;
    float* ws  = (float*)d_ws;

    hipLaunchKernelGGL(k_proj,       dim3(8*PROJ_TG), dim3(256), 0, stream,
                       x, W_in, W_delta, b_delta, W_B, b_B, W_C, b_C, ws);
    hipLaunchKernelGGL(k_abar_scan1, dim3(NB*NSEG),   dim3(512), 0, stream, A, ws);
    hipLaunchKernelGGL(k_scan2_out,  dim3(128),       dim3(256), 0, stream,
                       x, W_out, ln_w, ln_b, ws, out);
}